// Round 1
// baseline (1048.282 us; speedup 1.0000x reference)
//
#include <hip/hip_runtime.h>
#include <hip/hip_bf16.h>
#include <stdint.h>

// SparseMoE: B=8,T=4096 -> N=32768 tokens, D=512, H=2048, 8 experts, top-2, capacity=8192.
// Plan: fp32 router (exact selection) + capacity scan, bf16 MFMA expert GEMMs (m97-style),
// fused weighted scatter epilogue. Experts sequential on stream -> no atomics.

#define NTOK     32768
#define DMODEL   512
#define HDIM     2048
#define NEXP     8
#define CAPACITY 8192

typedef __attribute__((ext_vector_type(4))) float f32x4;
typedef __attribute__((ext_vector_type(8))) short s16x8;

#define GLOBAL_AS __attribute__((address_space(1)))
#define LDS_AS    __attribute__((address_space(3)))

__device__ __forceinline__ void gload16(const void* g, void* l) {
  // async global->LDS, 16B/lane; LDS dest is wave-uniform base + lane*16
  __builtin_amdgcn_global_load_lds((const GLOBAL_AS void*)g, (LDS_AS void*)l, 16, 0, 0);
}

// ---------------- fp32 -> bf16 convert (vectorized) ----------------
__global__ __launch_bounds__(256) void cvt_bf16_kernel(const float* __restrict__ s,
                                                       __hip_bfloat16* __restrict__ d, int n) {
  int stride = gridDim.x * blockDim.x * 4;
  for (int i = (blockIdx.x * blockDim.x + threadIdx.x) * 4; i < n; i += stride) {
    float4 v = *(const float4*)(s + i);
    union { __hip_bfloat16 b[4]; ushort4 u; } cv;
    cv.b[0] = __float2bfloat16(v.x);
    cv.b[1] = __float2bfloat16(v.y);
    cv.b[2] = __float2bfloat16(v.z);
    cv.b[3] = __float2bfloat16(v.w);
    *(ushort4*)(d + i) = cv.u;
  }
}

// ---------------- router: noisy top-2, exact fp32 ----------------
__global__ __launch_bounds__(256) void router_kernel(
    const float* __restrict__ x, const float* __restrict__ noise,
    const float* __restrict__ Ww, const float* __restrict__ bw,
    const float* __restrict__ Wn, const float* __restrict__ bn,
    int2* __restrict__ re, float2* __restrict__ rp) {
  const int tok = blockIdx.x * 256 + threadIdx.x;
  float acc[16];
#pragma unroll
  for (int e = 0; e < 16; e++) acc[e] = 0.f;
  const float4* xv4 = (const float4*)(x + (size_t)tok * DMODEL);
  const float4* Wwv = (const float4*)Ww;  // uniform index -> scalar loads
  const float4* Wnv = (const float4*)Wn;
  for (int k = 0; k < DMODEL / 4; k++) {
    const float4 xv = xv4[k];
#pragma unroll
    for (int e = 0; e < 8; e++) {
      const float4 a = Wwv[e * (DMODEL / 4) + k];
      acc[e] += xv.x * a.x + xv.y * a.y + xv.z * a.z + xv.w * a.w;
      const float4 b = Wnv[e * (DMODEL / 4) + k];
      acc[8 + e] += xv.x * b.x + xv.y * b.y + xv.z * b.z + xv.w * b.w;
    }
  }
  float nz[8];
  *(float4*)&nz[0] = ((const float4*)(noise + (size_t)tok * 8))[0];
  *(float4*)&nz[4] = ((const float4*)(noise + (size_t)tok * 8))[1];
  float noisy[8];
#pragma unroll
  for (int e = 0; e < 8; e++) {
    float z = acc[8 + e] + bn[e];
    float spv = fmaxf(z, 0.f) + log1pf(expf(-fabsf(z)));  // jax.nn.softplus = logaddexp(z,0)
    noisy[e] = acc[e] + bw[e] + nz[e] * spv;
  }
  // top-2, ties -> lower index (matches jax.lax.top_k)
  int i0 = 0; float v0 = noisy[0];
#pragma unroll
  for (int e = 1; e < 8; e++)
    if (noisy[e] > v0) { v0 = noisy[e]; i0 = e; }
  int i1 = -1; float v1 = -3.4e38f;
#pragma unroll
  for (int e = 0; e < 8; e++)
    if (e != i0 && noisy[e] > v1) { v1 = noisy[e]; i1 = e; }
  float ex = expf(v1 - v0);          // <= 1
  float inv = 1.f / (1.f + ex);      // softmax over the two top values
  re[tok] = make_int2(i0, i1);
  rp[tok] = make_float2(inv, ex * inv);
}

// ---------------- per-expert capacity scan (token order == reference cumsum) ----------------
__global__ __launch_bounds__(1024) void scan_kernel(const int2* __restrict__ re,
                                                    const float2* __restrict__ rp,
                                                    int* __restrict__ tokl,
                                                    float* __restrict__ wgtl) {
  const int e = blockIdx.x;
  const int tid = threadIdx.x;
  const int lane = tid & 63, wid = tid >> 6;
  __shared__ int wcount[16];
  int base = 0;
  for (int c = 0; c < NTOK; c += 1024) {
    const int t = c + tid;
    const int2 ee = re[t];
    const float2 pp = rp[t];
    const bool m = (ee.x == e) || (ee.y == e);
    unsigned long long bal = __ballot(m);
    int lanepre = __popcll(bal & ((1ull << lane) - 1ull));
    if (lane == 0) wcount[wid] = __popcll(bal);
    __syncthreads();
    int woff = 0, ctot = 0;
#pragma unroll
    for (int w = 0; w < 16; w++) {
      int cw = wcount[w];
      woff += (w < wid) ? cw : 0;
      ctot += cw;
    }
    const int pos = base + woff + lanepre;
    if (m && pos < CAPACITY) {
      tokl[(size_t)e * CAPACITY + pos] = t;
      wgtl[(size_t)e * CAPACITY + pos] = (ee.x == e) ? pp.x : pp.y;
    }
    base += ctot;
    __syncthreads();  // protect wcount before next chunk
  }
}

// ---------------- GEMM1: h = relu(gather(xb) @ W1[e]^T + b1[e]) ----------------
// 128x128 tile, BK=32, 4 waves (2x2 of 64x64), mfma 16x16x32 bf16, global_load_lds staging.
__global__ __launch_bounds__(256) void gemm1_kernel(
    const __hip_bfloat16* __restrict__ xb,   // [NTOK][512]
    const __hip_bfloat16* __restrict__ w1,   // [2048][512] (this expert)
    const float* __restrict__ b1,            // [2048]
    const int* __restrict__ tokl,            // [CAPACITY]
    __hip_bfloat16* __restrict__ h) {        // [CAPACITY][2048]
  __shared__ char lds[16384];  // A [128][32]bf16 @0, B [128][32]bf16 @8192
  const int tid = threadIdx.x;
  const int lane = tid & 63, wid = tid >> 6;
  const int bm = blockIdx.y, bn = blockIdx.x;
  const int r = tid >> 2;
  const int c8 = (tid & 3) * 8;

  const int tA0 = tokl[bm * 128 + r];
  const int tA1 = tokl[bm * 128 + 64 + r];
  const __hip_bfloat16* gA0 = xb + (size_t)tA0 * DMODEL + c8;
  const __hip_bfloat16* gA1 = xb + (size_t)tA1 * DMODEL + c8;
  const __hip_bfloat16* gB0 = w1 + (size_t)(bn * 128 + r) * DMODEL + c8;
  const __hip_bfloat16* gB1 = w1 + (size_t)(bn * 128 + 64 + r) * DMODEL + c8;

  char* lA = lds + wid * 1024;           // wave-uniform LDS dests
  char* lB = lds + 8192 + wid * 1024;

  f32x4 acc[4][4];
#pragma unroll
  for (int m = 0; m < 4; m++)
#pragma unroll
    for (int n = 0; n < 4; n++) acc[m][n] = (f32x4){0.f, 0.f, 0.f, 0.f};

  const int wr = wid >> 1, wc = wid & 1;
  for (int ks = 0; ks < DMODEL; ks += 32) {
    gload16(gA0 + ks, lA);
    gload16(gA1 + ks, lA + 4096);
    gload16(gB0 + ks, lB);
    gload16(gB1 + ks, lB + 4096);
    __syncthreads();  // compiler drains vmcnt before barrier
    s16x8 af[4], bf[4];
#pragma unroll
    for (int m = 0; m < 4; m++) {
      int off = (wr * 64 + m * 16 + (lane & 15)) * 64 + (lane >> 4) * 16;
      af[m] = *(const s16x8*)(lds + off);
    }
#pragma unroll
    for (int n = 0; n < 4; n++) {
      int off = (wc * 64 + n * 16 + (lane & 15)) * 64 + (lane >> 4) * 16;
      bf[n] = *(const s16x8*)(lds + 8192 + off);
    }
#pragma unroll
    for (int m = 0; m < 4; m++)
#pragma unroll
      for (int n = 0; n < 4; n++)
        acc[m][n] = __builtin_amdgcn_mfma_f32_16x16x32_bf16(af[m], bf[n], acc[m][n], 0, 0, 0);
    __syncthreads();
  }
  // epilogue: C/D layout col=lane&15, row=(lane>>4)*4+q  [m89-verified]
#pragma unroll
  for (int n = 0; n < 4; n++) {
    const int col = bn * 128 + wc * 64 + n * 16 + (lane & 15);
    const float bias = b1[col];
#pragma unroll
    for (int m = 0; m < 4; m++) {
      const int row0 = bm * 128 + wr * 64 + m * 16 + (lane >> 4) * 4;
#pragma unroll
      for (int q = 0; q < 4; q++) {
        float v = acc[m][n][q] + bias;
        h[(size_t)(row0 + q) * HDIM + col] = __float2bfloat16(fmaxf(v, 0.f));
      }
    }
  }
}

// ---------------- GEMM2: out[tok] += w * (h @ W2[e]^T + b2[e]) ----------------
// 128x64 tile (512 blocks -> 2/CU for latency hiding at N=512), fused scatter RMW.
__global__ __launch_bounds__(256) void gemm2_kernel(
    const __hip_bfloat16* __restrict__ h,    // [CAPACITY][2048]
    const __hip_bfloat16* __restrict__ w2,   // [512][2048] (this expert)
    const float* __restrict__ b2,            // [512]
    const int* __restrict__ tokl, const float* __restrict__ wgtl,
    float* __restrict__ out) {               // [NTOK][512]
  __shared__ char lds[12288];  // A [128][32] @0, B [64][32] @8192
  const int tid = threadIdx.x;
  const int lane = tid & 63, wid = tid >> 6;
  const int bm = blockIdx.y, bn = blockIdx.x;
  const int r = tid >> 2;
  const int c8 = (tid & 3) * 8;

  const __hip_bfloat16* gA0 = h + (size_t)(bm * 128 + r) * HDIM + c8;
  const __hip_bfloat16* gA1 = h + (size_t)(bm * 128 + 64 + r) * HDIM + c8;
  const __hip_bfloat16* gB0 = w2 + (size_t)(bn * 64 + r) * HDIM + c8;

  char* lA = lds + wid * 1024;
  char* lB = lds + 8192 + wid * 1024;

  f32x4 acc[4][2];
#pragma unroll
  for (int m = 0; m < 4; m++)
#pragma unroll
    for (int n = 0; n < 2; n++) acc[m][n] = (f32x4){0.f, 0.f, 0.f, 0.f};

  const int wr = wid >> 1, wc = wid & 1;
  for (int ks = 0; ks < HDIM; ks += 32) {
    gload16(gA0 + ks, lA);
    gload16(gA1 + ks, lA + 4096);
    gload16(gB0 + ks, lB);
    __syncthreads();
    s16x8 af[4], bf[2];
#pragma unroll
    for (int m = 0; m < 4; m++) {
      int off = (wr * 64 + m * 16 + (lane & 15)) * 64 + (lane >> 4) * 16;
      af[m] = *(const s16x8*)(lds + off);
    }
#pragma unroll
    for (int n = 0; n < 2; n++) {
      int off = (wc * 32 + n * 16 + (lane & 15)) * 64 + (lane >> 4) * 16;
      bf[n] = *(const s16x8*)(lds + 8192 + off);
    }
#pragma unroll
    for (int m = 0; m < 4; m++)
#pragma unroll
      for (int n = 0; n < 2; n++)
        acc[m][n] = __builtin_amdgcn_mfma_f32_16x16x32_bf16(af[m], bf[n], acc[m][n], 0, 0, 0);
    __syncthreads();
  }
  int cols[2]; float biasv[2];
#pragma unroll
  for (int n = 0; n < 2; n++) {
    cols[n] = bn * 64 + wc * 32 + n * 16 + (lane & 15);
    biasv[n] = b2[cols[n]];
  }
#pragma unroll
  for (int m = 0; m < 4; m++) {
    const int row0 = bm * 128 + wr * 64 + m * 16 + (lane >> 4) * 4;
#pragma unroll
    for (int q = 0; q < 4; q++) {
      const int slot = row0 + q;
      const int t = tokl[slot];
      const float w = wgtl[slot];
      if (w != 0.f) {  // skip empty/overflow slots (avoids dump-slot RMW race on token 0)
        float* op = out + (size_t)t * DMODEL;
        op[cols[0]] += (acc[m][0][q] + biasv[0]) * w;
        op[cols[1]] += (acc[m][1][q] + biasv[1]) * w;
      }
    }
  }
}

extern "C" void kernel_launch(void* const* d_in, const int* in_sizes, int n_in,
                              void* d_out, int out_size, void* d_ws, size_t ws_size,
                              hipStream_t stream) {
  const float* x  = (const float*)d_in[0];
  const float* noise = (const float*)d_in[1];
  const float* Ww = (const float*)d_in[2];
  const float* bw = (const float*)d_in[3];
  const float* Wn = (const float*)d_in[4];
  const float* bn = (const float*)d_in[5];
  const float* W1 = (const float*)d_in[6];
  const float* b1 = (const float*)d_in[7];
  const float* W2 = (const float*)d_in[8];
  const float* b2 = (const float*)d_in[9];
  float* out = (float*)d_out;

  // workspace layout (bytes)
  char* ws = (char*)d_ws;
  __hip_bfloat16* xb  = (__hip_bfloat16*)(ws);                 // 32 MB  [NTOK][512]
  __hip_bfloat16* w1b = (__hip_bfloat16*)(ws + 33554432);      // 16 MB  [8][2048][512]
  __hip_bfloat16* w2b = (__hip_bfloat16*)(ws + 50331648);      // 16 MB  [8][512][2048]
  __hip_bfloat16* hb  = (__hip_bfloat16*)(ws + 67108864);      // 32 MB  [8192][2048] (per-expert reuse)
  int2*   re   = (int2*)(ws + 100663296);                      // 256 KB
  float2* rp   = (float2*)(ws + 100925440);                    // 256 KB
  int*    tokl = (int*)(ws + 101187584);                       // 256 KB [8][8192]
  float*  wgtl = (float*)(ws + 101449728);                     // 256 KB [8][8192]

  hipMemsetAsync(d_out, 0, (size_t)NTOK * DMODEL * sizeof(float), stream);
  hipMemsetAsync(tokl, 0, 2 * NEXP * CAPACITY * sizeof(int), stream);  // tokl+wgtl contiguous

  cvt_bf16_kernel<<<2048, 256, 0, stream>>>(x, xb, NTOK * DMODEL);
  cvt_bf16_kernel<<<1024, 256, 0, stream>>>(W1, w1b, NEXP * HDIM * DMODEL);
  cvt_bf16_kernel<<<1024, 256, 0, stream>>>(W2, w2b, NEXP * HDIM * DMODEL);
  router_kernel<<<NTOK / 256, 256, 0, stream>>>(x, noise, Ww, bw, Wn, bn, re, rp);
  scan_kernel<<<NEXP, 1024, 0, stream>>>(re, rp, tokl, wgtl);

  for (int e = 0; e < NEXP; e++) {
    gemm1_kernel<<<dim3(HDIM / 128, CAPACITY / 128), 256, 0, stream>>>(
        xb, w1b + (size_t)e * HDIM * DMODEL, b1 + (size_t)e * HDIM,
        tokl + (size_t)e * CAPACITY, hb);
    gemm2_kernel<<<dim3(DMODEL / 64, CAPACITY / 128), 256, 0, stream>>>(
        hb, w2b + (size_t)e * DMODEL * HDIM, b2 + (size_t)e * DMODEL,
        tokl + (size_t)e * CAPACITY, wgtl + (size_t)e * CAPACITY, out);
  }
}

// Round 3
// 979.985 us; speedup vs baseline: 1.0697x; 1.0697x over previous
//
#include <hip/hip_runtime.h>
#include <hip/hip_bf16.h>
#include <stdint.h>

// SparseMoE: N=32768 tokens, D=512, H=2048, 8 experts, top-2, capacity=8192.
// R2 (resubmit after infra timeout): wave-per-token router (fused x->bf16), prefetched scan,
//     gemm1 = 256x256/BK=64 8-phase counted-vmcnt template (T2 swizzle + T3/T4 + T5).
//     gemm2 frozen from R1 (port next round once template is validated).

#define NTOK     32768
#define DMODEL   512
#define HDIM     2048
#define NEXP     8
#define CAPACITY 8192

typedef __attribute__((ext_vector_type(4))) float f32x4;
typedef __attribute__((ext_vector_type(8))) short s16x8;

#define GLOBAL_AS __attribute__((address_space(1)))
#define LDS_AS    __attribute__((address_space(3)))

__device__ __forceinline__ void gload16(const void* g, void* l) {
  // async global->LDS, 16B/lane; LDS dest is wave-uniform base + lane*16
  __builtin_amdgcn_global_load_lds((const GLOBAL_AS void*)g, (LDS_AS void*)l, 16, 0, 0);
}

// ---------------- fp32 -> bf16 convert (weights) ----------------
__global__ __launch_bounds__(256) void cvt_bf16_kernel(const float* __restrict__ s,
                                                       __hip_bfloat16* __restrict__ d, int n) {
  int stride = gridDim.x * blockDim.x * 4;
  for (int i = (blockIdx.x * blockDim.x + threadIdx.x) * 4; i < n; i += stride) {
    float4 v = *(const float4*)(s + i);
    union { __hip_bfloat16 b[4]; ushort4 u; } cv;
    cv.b[0] = __float2bfloat16(v.x);
    cv.b[1] = __float2bfloat16(v.y);
    cv.b[2] = __float2bfloat16(v.z);
    cv.b[3] = __float2bfloat16(v.w);
    *(ushort4*)(d + i) = cv.u;
  }
}

// ---------------- router: wave-per-token, fused x->bf16 ----------------
__global__ __launch_bounds__(256) void router_kernel(
    const float* __restrict__ x, const float* __restrict__ noise,
    const float* __restrict__ Ww, const float* __restrict__ bw,
    const float* __restrict__ Wn, const float* __restrict__ bn,
    __hip_bfloat16* __restrict__ xb, int2* __restrict__ re, float2* __restrict__ rp) {
  const int tid = threadIdx.x;
  const int lane = tid & 63;
  const int tok = blockIdx.x * 4 + (tid >> 6);
  const float* xrow = x + (size_t)tok * DMODEL;
  const float4 xa = *(const float4*)(xrow + 4 * lane);          // cols 4l..4l+3
  const float4 xc = *(const float4*)(xrow + 256 + 4 * lane);    // cols 256+4l..

  // fused bf16 conversion of x (coalesced ushort4 stores)
  union { __hip_bfloat16 b[4]; ushort4 u; } c0, c1;
  c0.b[0] = __float2bfloat16(xa.x); c0.b[1] = __float2bfloat16(xa.y);
  c0.b[2] = __float2bfloat16(xa.z); c0.b[3] = __float2bfloat16(xa.w);
  c1.b[0] = __float2bfloat16(xc.x); c1.b[1] = __float2bfloat16(xc.y);
  c1.b[2] = __float2bfloat16(xc.z); c1.b[3] = __float2bfloat16(xc.w);
  *(ushort4*)(xb + (size_t)tok * DMODEL + 4 * lane) = c0.u;
  *(ushort4*)(xb + (size_t)tok * DMODEL + 256 + 4 * lane) = c1.u;

  float acc[16];
#pragma unroll
  for (int e = 0; e < 8; e++) {
    const float4 wa = *(const float4*)(Ww + e * DMODEL + 4 * lane);
    const float4 wc2 = *(const float4*)(Ww + e * DMODEL + 256 + 4 * lane);
    acc[e] = xa.x * wa.x + xa.y * wa.y + xa.z * wa.z + xa.w * wa.w
           + xc.x * wc2.x + xc.y * wc2.y + xc.z * wc2.z + xc.w * wc2.w;
    const float4 na = *(const float4*)(Wn + e * DMODEL + 4 * lane);
    const float4 nc = *(const float4*)(Wn + e * DMODEL + 256 + 4 * lane);
    acc[8 + e] = xa.x * na.x + xa.y * na.y + xa.z * na.z + xa.w * na.w
               + xc.x * nc.x + xc.y * nc.y + xc.z * nc.z + xc.w * nc.w;
  }
  // butterfly reduce across 64 lanes (all lanes end with full sums)
#pragma unroll
  for (int e = 0; e < 16; e++) {
#pragma unroll
    for (int off = 32; off >= 1; off >>= 1)
      acc[e] += __shfl_xor(acc[e], off, 64);
  }
  // all lanes redundantly finish; lane 0 stores
  const float4 nz0 = *(const float4*)(noise + (size_t)tok * 8);
  const float4 nz1 = *(const float4*)(noise + (size_t)tok * 8 + 4);
  float nzv[8] = {nz0.x, nz0.y, nz0.z, nz0.w, nz1.x, nz1.y, nz1.z, nz1.w};
  float noisy[8];
#pragma unroll
  for (int e = 0; e < 8; e++) {
    float z = acc[8 + e] + bn[e];
    float spv = fmaxf(z, 0.f) + log1pf(expf(-fabsf(z)));  // softplus
    noisy[e] = acc[e] + bw[e] + nzv[e] * spv;
  }
  int i0 = 0; float v0 = noisy[0];
#pragma unroll
  for (int e = 1; e < 8; e++)
    if (noisy[e] > v0) { v0 = noisy[e]; i0 = e; }
  int i1 = -1; float v1 = -3.4e38f;
#pragma unroll
  for (int e = 0; e < 8; e++)
    if (e != i0 && noisy[e] > v1) { v1 = noisy[e]; i1 = e; }
  float ex = expf(v1 - v0);
  float inv = 1.f / (1.f + ex);
  if (lane == 0) {
    re[tok] = make_int2(i0, i1);
    rp[tok] = make_float2(inv, ex * inv);
  }
}

// ---------------- per-expert capacity scan (token order == reference cumsum) ----------------
__global__ __launch_bounds__(1024) void scan_kernel(const int2* __restrict__ re,
                                                    const float2* __restrict__ rp,
                                                    int* __restrict__ tokl,
                                                    float* __restrict__ wgtl) {
  const int e = blockIdx.x;
  const int tid = threadIdx.x;
  const int lane = tid & 63, wid = tid >> 6;
  __shared__ int wcount[16];
  int base = 0;
  int2 ee = re[tid];
  float2 pp = rp[tid];
  for (int c = 0; c < NTOK; c += 1024) {
    // prefetch next chunk while processing this one
    int2 ee_n; float2 pp_n;
    const int tn = c + 1024 + tid;
    if (tn < NTOK) { ee_n = re[tn]; pp_n = rp[tn]; }
    const int t = c + tid;
    const bool m = (ee.x == e) || (ee.y == e);
    unsigned long long bal = __ballot(m);
    int lanepre = __popcll(bal & ((1ull << lane) - 1ull));
    if (lane == 0) wcount[wid] = __popcll(bal);
    __syncthreads();
    int woff = 0, ctot = 0;
#pragma unroll
    for (int w = 0; w < 16; w++) {
      int cw = wcount[w];
      woff += (w < wid) ? cw : 0;
      ctot += cw;
    }
    const int pos = base + woff + lanepre;
    if (m && pos < CAPACITY) {
      tokl[(size_t)e * CAPACITY + pos] = t;
      wgtl[(size_t)e * CAPACITY + pos] = (ee.x == e) ? pp.x : pp.y;
    }
    base += ctot;
    __syncthreads();  // protect wcount before next chunk
    ee = ee_n; pp = pp_n;
  }
}

// ---------------- GEMM1: h = relu(gather(xb) @ W1[e]^T + b1[e]) ----------------
// 256x256 tile, BK=64, 8 waves (2Mx4N), 8-phase counted-vmcnt schedule (T2+T3+T4+T5).
// LDS 128KB: 2 dbuf x {A 32KB (2 halves by mh), B 32KB (2 halves by nh)}.
// Physical A row p in half mh maps to logical row (p>>6)*128 + mh*64 + (p&63);
// physical B row p in half nh maps to logical row (p>>5)*64 + nh*32 + (p&31).
// Col swizzle: 16B slot ^= (prow&7), applied as inverse-swizzled global SOURCE
// (linear global_load_lds dest) + swizzled ds_read (rule #21).
#define MFMA_QUAD(MH, NH, BF)                                                        \
  _Pragma("unroll") for (int m = 0; m < 4; m++)                                      \
  _Pragma("unroll") for (int n = 0; n < 2; n++)                                      \
  _Pragma("unroll") for (int kk = 0; kk < 2; kk++)                                   \
    acc[(MH)*4 + m][(NH)*2 + n] = __builtin_amdgcn_mfma_f32_16x16x32_bf16(           \
        af[m][kk], BF[n][kk], acc[(MH)*4 + m][(NH)*2 + n], 0, 0, 0);

__global__ __launch_bounds__(512, 2) void gemm1_kernel(
    const __hip_bfloat16* __restrict__ xb,   // [NTOK][512]
    const __hip_bfloat16* __restrict__ w1,   // [2048][512] (this expert)
    const float* __restrict__ b1,            // [2048]
    const int* __restrict__ tokl,            // [CAPACITY]
    __hip_bfloat16* __restrict__ h) {        // [CAPACITY][2048]
  extern __shared__ char lds[];              // 131072 B
  const int tid = threadIdx.x;
  const int lane = tid & 63;
  const int wid = tid >> 6;
  const int wr = wid >> 2, wc = wid & 3;
  const int bn = blockIdx.x, bm = blockIdx.y;

  // ---- stage source pointers (inverse-swizzled col; row gather precomputed) ----
  const int rowsel = tid >> 3;                                // 0..63
  const int colsw = 8 * ((tid & 7) ^ (rowsel & 7));           // element offset
  const __hip_bfloat16* srcA[2][2];
  const __hip_bfloat16* srcB[2][2];
#pragma unroll
  for (int hh = 0; hh < 2; hh++)
#pragma unroll
    for (int j = 0; j < 2; j++) {
      const int arow = j * 128 + hh * 64 + rowsel;            // logical A row
      srcA[hh][j] = xb + (size_t)tokl[bm * 256 + arow] * DMODEL + colsw;
      const int prow = j * 64 + rowsel;                        // physical B row in half
      const int brow = (prow >> 5) * 64 + hh * 32 + (prow & 31);
      srcB[hh][j] = w1 + (size_t)(bn * 256 + brow) * DMODEL + colsw;
    }
  const int wub = wid * 1024;  // wave-uniform LDS dest offset within an 8KB call

  auto stageA = [&](int hh, int t) {
    char* base = lds + ((t & 1) * 65536) + hh * 16384 + wub;
    gload16(srcA[hh][0] + t * 64, base);
    gload16(srcA[hh][1] + t * 64, base + 8192);
  };
  auto stageB = [&](int hh, int t) {
    char* base = lds + ((t & 1) * 65536) + 32768 + hh * 16384 + wub;
    gload16(srcB[hh][0] + t * 64, base);
    gload16(srcB[hh][1] + t * 64, base + 8192);
  };

  // ---- read-side per-lane offsets (swizzled) ----
  const int cs0 = ((lane >> 4) * 16) ^ ((lane & 7) << 4);     // kk=0 col byte
  const int arowoff = (wr * 64 + (lane & 15)) * 128;
  const int browoff = (wc * 32 + (lane & 15)) * 128;

  f32x4 acc[8][4];
#pragma unroll
  for (int m = 0; m < 8; m++)
#pragma unroll
    for (int n = 0; n < 4; n++) acc[m][n] = (f32x4){0.f, 0.f, 0.f, 0.f};

  // ---- prologue: tile0 fully + tile1 {Ah0,Bh0,Bh1}; Ah1(1) staged at w0/P1 ----
  stageA(0, 0); stageB(0, 0); stageA(1, 0); stageB(1, 0);
  stageA(0, 1); stageB(0, 1); stageB(1, 1);
  asm volatile("s_waitcnt vmcnt(6)" ::: "memory");   // tile0's 8 loads landed
  __builtin_amdgcn_s_barrier();

  s16x8 af[4][2], bf0[2][2], bf1[2][2];
  const int NT = DMODEL / 64;  // 8 K-tiles
  for (int w = 0; w < NT; w++) {
    char* La = lds + (w & 1) * 65536;
    char* Lb = La + 32768;
    // ---- P1: quadrant (mh0, nh0); stage Ah1(w+1) -> other buf
#pragma unroll
    for (int m = 0; m < 4; m++)
#pragma unroll
      for (int kk = 0; kk < 2; kk++)
        af[m][kk] = *(const s16x8*)(La + arowoff + m * 2048 + (cs0 ^ (kk << 6)));
#pragma unroll
    for (int n = 0; n < 2; n++)
#pragma unroll
      for (int kk = 0; kk < 2; kk++)
        bf0[n][kk] = *(const s16x8*)(Lb + browoff + n * 2048 + (cs0 ^ (kk << 6)));
    if (w + 1 < NT) stageA(1, w + 1);
    __builtin_amdgcn_s_barrier();
    asm volatile("s_waitcnt lgkmcnt(0)" ::: "memory");
    __builtin_amdgcn_sched_barrier(0);
    __builtin_amdgcn_s_setprio(1);
    MFMA_QUAD(0, 0, bf0)
    __builtin_amdgcn_s_setprio(0);
    __builtin_amdgcn_s_barrier();
    // ---- P2: quadrant (mh0, nh1); stage Ah0(w+2) -> cur buf (Ah0 consumed @P1)
#pragma unroll
    for (int n = 0; n < 2; n++)
#pragma unroll
      for (int kk = 0; kk < 2; kk++)
        bf1[n][kk] = *(const s16x8*)(Lb + 16384 + browoff + n * 2048 + (cs0 ^ (kk << 6)));
    if (w + 2 < NT) stageA(0, w + 2);
    __builtin_amdgcn_s_barrier();
    asm volatile("s_waitcnt lgkmcnt(0)" ::: "memory");
    __builtin_amdgcn_sched_barrier(0);
    __builtin_amdgcn_s_setprio(1);
    MFMA_QUAD(0, 1, bf1)
    __builtin_amdgcn_s_setprio(0);
    __builtin_amdgcn_s_barrier();
    // ---- P3: quadrant (mh1, nh0); stage Bh0(w+2) (Bh0 consumed @P1)
#pragma unroll
    for (int m = 0; m < 4; m++)
#pragma unroll
      for (int kk = 0; kk < 2; kk++)
        af[m][kk] = *(const s16x8*)(La + 16384 + arowoff + m * 2048 + (cs0 ^ (kk << 6)));
    if (w + 2 < NT) stageB(0, w + 2);
    __builtin_amdgcn_s_barrier();
    asm volatile("s_waitcnt lgkmcnt(0)" ::: "memory");
    __builtin_amdgcn_sched_barrier(0);
    __builtin_amdgcn_s_setprio(1);
    MFMA_QUAD(1, 0, bf0)
    __builtin_amdgcn_s_setprio(0);
    __builtin_amdgcn_s_barrier();
    // ---- P4: quadrant (mh1, nh1); stage Bh1(w+2) (Bh1 consumed @P2); boundary vmcnt
    if (w + 2 < NT) stageB(1, w + 2);
    if (w == NT - 2) { asm volatile("s_waitcnt vmcnt(0)" ::: "memory"); }
    else             { asm volatile("s_waitcnt vmcnt(6)" ::: "memory"); }
    __builtin_amdgcn_s_barrier();
    __builtin_amdgcn_s_setprio(1);
    MFMA_QUAD(1, 1, bf1)
    __builtin_amdgcn_s_setprio(0);
    __builtin_amdgcn_s_barrier();
  }

  // ---- epilogue: bias + relu + bf16 store (C/D: col=lane&15, row=(lane>>4)*4+q) ----
#pragma unroll
  for (int nn = 0; nn < 4; nn++) {
    const int col = bn * 256 + wc * 64 + nn * 16 + (lane & 15);
    const float bias = b1[col];
#pragma unroll
    for (int m = 0; m < 8; m++) {
      const int row0 = bm * 256 + wr * 128 + m * 16 + ((lane >> 4) << 2);
#pragma unroll
      for (int q = 0; q < 4; q++) {
        float v = acc[m][nn][q] + bias;
        h[(size_t)(row0 + q) * HDIM + col] = __float2bfloat16(fmaxf(v, 0.f));
      }
    }
  }
}

// ---------------- GEMM2 (frozen from R1): out[tok] += w * (h @ W2[e]^T + b2[e]) ----------------
__global__ __launch_bounds__(256) void gemm2_kernel(
    const __hip_bfloat16* __restrict__ h,    // [CAPACITY][2048]
    const __hip_bfloat16* __restrict__ w2,   // [512][2048] (this expert)
    const float* __restrict__ b2,            // [512]
    const int* __restrict__ tokl, const float* __restrict__ wgtl,
    float* __restrict__ out) {               // [NTOK][512]
  __shared__ char lds2[12288];  // A [128][32] @0, B [64][32] @8192
  const int tid = threadIdx.x;
  const int lane = tid & 63, wid = tid >> 6;
  const int bm = blockIdx.y, bn = blockIdx.x;
  const int r = tid >> 2;
  const int c8 = (tid & 3) * 8;

  const __hip_bfloat16* gA0 = h + (size_t)(bm * 128 + r) * HDIM + c8;
  const __hip_bfloat16* gA1 = h + (size_t)(bm * 128 + 64 + r) * HDIM + c8;
  const __hip_bfloat16* gB0 = w2 + (size_t)(bn * 64 + r) * HDIM + c8;

  char* lA = lds2 + wid * 1024;
  char* lB = lds2 + 8192 + wid * 1024;

  f32x4 acc[4][2];
#pragma unroll
  for (int m = 0; m < 4; m++)
#pragma unroll
    for (int n = 0; n < 2; n++) acc[m][n] = (f32x4){0.f, 0.f, 0.f, 0.f};

  const int wr = wid >> 1, wc = wid & 1;
  for (int ks = 0; ks < HDIM; ks += 32) {
    gload16(gA0 + ks, lA);
    gload16(gA1 + ks, lA + 4096);
    gload16(gB0 + ks, lB);
    __syncthreads();
    s16x8 af[4], bf[2];
#pragma unroll
    for (int m = 0; m < 4; m++) {
      int off = (wr * 64 + m * 16 + (lane & 15)) * 64 + (lane >> 4) * 16;
      af[m] = *(const s16x8*)(lds2 + off);
    }
#pragma unroll
    for (int n = 0; n < 2; n++) {
      int off = (wc * 32 + n * 16 + (lane & 15)) * 64 + (lane >> 4) * 16;
      bf[n] = *(const s16x8*)(lds2 + 8192 + off);
    }
#pragma unroll
    for (int m = 0; m < 4; m++)
#pragma unroll
      for (int n = 0; n < 2; n++)
        acc[m][n] = __builtin_amdgcn_mfma_f32_16x16x32_bf16(af[m], bf[n], acc[m][n], 0, 0, 0);
    __syncthreads();
  }
  int cols[2]; float biasv[2];
#pragma unroll
  for (int n = 0; n < 2; n++) {
    cols[n] = bn * 64 + wc * 32 + n * 16 + (lane & 15);
    biasv[n] = b2[cols[n]];
  }
#pragma unroll
  for (int m = 0; m < 4; m++) {
    const int row0 = bm * 128 + wr * 64 + m * 16 + (lane >> 4) * 4;
#pragma unroll
    for (int q = 0; q < 4; q++) {
      const int slot = row0 + q;
      const int t = tokl[slot];
      const float w = wgtl[slot];
      if (w != 0.f) {  // skip empty/overflow slots
        float* op = out + (size_t)t * DMODEL;
        op[cols[0]] += (acc[m][0][q] + biasv[0]) * w;
        op[cols[1]] += (acc[m][1][q] + biasv[1]) * w;
      }
    }
  }
}

extern "C" void kernel_launch(void* const* d_in, const int* in_sizes, int n_in,
                              void* d_out, int out_size, void* d_ws, size_t ws_size,
                              hipStream_t stream) {
  const float* x  = (const float*)d_in[0];
  const float* noise = (const float*)d_in[1];
  const float* Ww = (const float*)d_in[2];
  const float* bw = (const float*)d_in[3];
  const float* Wn = (const float*)d_in[4];
  const float* bn = (const float*)d_in[5];
  const float* W1 = (const float*)d_in[6];
  const float* b1 = (const float*)d_in[7];
  const float* W2 = (const float*)d_in[8];
  const float* b2 = (const float*)d_in[9];
  float* out = (float*)d_out;

  // workspace layout (bytes)
  char* ws = (char*)d_ws;
  __hip_bfloat16* xb  = (__hip_bfloat16*)(ws);                 // 32 MB  [NTOK][512]
  __hip_bfloat16* w1b = (__hip_bfloat16*)(ws + 33554432);      // 16 MB  [8][2048][512]
  __hip_bfloat16* w2b = (__hip_bfloat16*)(ws + 50331648);      // 16 MB  [8][512][2048]
  __hip_bfloat16* hb  = (__hip_bfloat16*)(ws + 67108864);      // 32 MB  [8192][2048]
  int2*   re   = (int2*)(ws + 100663296);                      // 256 KB
  float2* rp   = (float2*)(ws + 100925440);                    // 256 KB
  int*    tokl = (int*)(ws + 101187584);                       // 256 KB [8][8192]
  float*  wgtl = (float*)(ws + 101449728);                     // 256 KB [8][8192]

  // allow 128KB dynamic LDS for gemm1 (host-side attr, graph-capture safe)
  (void)hipFuncSetAttribute((const void*)gemm1_kernel,
                            hipFuncAttributeMaxDynamicSharedMemorySize, 131072);

  hipMemsetAsync(d_out, 0, (size_t)NTOK * DMODEL * sizeof(float), stream);
  hipMemsetAsync(tokl, 0, 2 * NEXP * CAPACITY * sizeof(int), stream);  // tokl+wgtl contiguous

  cvt_bf16_kernel<<<1024, 256, 0, stream>>>(W1, w1b, NEXP * HDIM * DMODEL);
  cvt_bf16_kernel<<<1024, 256, 0, stream>>>(W2, w2b, NEXP * HDIM * DMODEL);
  router_kernel<<<NTOK / 4, 256, 0, stream>>>(x, noise, Ww, bw, Wn, bn, xb, re, rp);
  scan_kernel<<<NEXP, 1024, 0, stream>>>(re, rp, tokl, wgtl);

  for (int e = 0; e < NEXP; e++) {
    gemm1_kernel<<<dim3(HDIM / 256, CAPACITY / 256), 512, 131072, stream>>>(
        xb, w1b + (size_t)e * HDIM * DMODEL, b1 + (size_t)e * HDIM,
        tokl + (size_t)e * CAPACITY, hb);
    gemm2_kernel<<<dim3(DMODEL / 64, CAPACITY / 128), 256, 0, stream>>>(
        hb, w2b + (size_t)e * DMODEL * HDIM, b2 + (size_t)e * DMODEL,
        tokl + (size_t)e * CAPACITY, wgtl + (size_t)e * CAPACITY, out);
  }
}

// Round 4
// 797.038 us; speedup vs baseline: 1.3152x; 1.2295x over previous
//
#include <hip/hip_runtime.h>
#include <hip/hip_bf16.h>
#include <stdint.h>

// SparseMoE: N=32768 tokens, D=512, H=2048, 8 experts, top-2, capacity=8192.
// R4: router = 4-lanes-per-token (2-step butterfly); gemm2 rewritten 128x128/BK=64
//     swizzled + expert-pair z-batch + atomic scatter; gemm1 8-phase pair-batched.

#define NTOK     32768
#define DMODEL   512
#define HDIM     2048
#define NEXP     8
#define CAPACITY 8192

typedef __attribute__((ext_vector_type(4))) float f32x4;
typedef __attribute__((ext_vector_type(8))) short s16x8;

#define GLOBAL_AS __attribute__((address_space(1)))
#define LDS_AS    __attribute__((address_space(3)))

__device__ __forceinline__ void gload16(const void* g, void* l) {
  // async global->LDS, 16B/lane; LDS dest is wave-uniform base (+ lane*16 by HW)
  __builtin_amdgcn_global_load_lds((const GLOBAL_AS void*)g, (LDS_AS void*)l, 16, 0, 0);
}

// ---------------- fp32 -> bf16 convert (weights) ----------------
__global__ __launch_bounds__(256) void cvt_bf16_kernel(const float* __restrict__ s,
                                                       __hip_bfloat16* __restrict__ d, int n) {
  int stride = gridDim.x * blockDim.x * 4;
  for (int i = (blockIdx.x * blockDim.x + threadIdx.x) * 4; i < n; i += stride) {
    float4 v = *(const float4*)(s + i);
    union { __hip_bfloat16 b[4]; ushort4 u; } cv;
    cv.b[0] = __float2bfloat16(v.x);
    cv.b[1] = __float2bfloat16(v.y);
    cv.b[2] = __float2bfloat16(v.z);
    cv.b[3] = __float2bfloat16(v.w);
    *(ushort4*)(d + i) = cv.u;
  }
}

// ---------------- router: 4 lanes per token, fused x->bf16 ----------------
// Lane group of 4 covers D=512 in quarters; 16 tokens per wave.
// Butterfly = 2 steps (xor 1,2). Tail computed redundantly by the 4 lanes.
__global__ __launch_bounds__(256) void router_kernel(
    const float* __restrict__ x, const float* __restrict__ noise,
    const float* __restrict__ Ww, const float* __restrict__ bw,
    const float* __restrict__ Wn, const float* __restrict__ bn,
    __hip_bfloat16* __restrict__ xb, int2* __restrict__ re, float2* __restrict__ rp) {
  const int tid = threadIdx.x;
  const int q = tid & 3;                       // quarter of D
  const int tok = blockIdx.x * 64 + (tid >> 2);
  const float* xq = x + (size_t)tok * DMODEL + q * 128;
  const float* wwq = Ww + q * 128;
  const float* wnq = Wn + q * 128;
  __hip_bfloat16* xbq = xb + (size_t)tok * DMODEL + q * 128;

  float acc[16];
#pragma unroll
  for (int e = 0; e < 16; e++) acc[e] = 0.f;
  float4 xprev;
#pragma unroll 2
  for (int k = 0; k < 32; k++) {
    const float4 xv = *(const float4*)(xq + 4 * k);
#pragma unroll
    for (int e = 0; e < 8; e++) {
      const float4 a = *(const float4*)(wwq + e * DMODEL + 4 * k);
      acc[e] = fmaf(xv.w, a.w, fmaf(xv.z, a.z, fmaf(xv.y, a.y, fmaf(xv.x, a.x, acc[e]))));
      const float4 b = *(const float4*)(wnq + e * DMODEL + 4 * k);
      acc[8 + e] = fmaf(xv.w, b.w, fmaf(xv.z, b.z, fmaf(xv.y, b.y, fmaf(xv.x, b.x, acc[8 + e]))));
    }
    if (k & 1) {  // pack 8 floats -> 16B bf16 store
      union { __hip_bfloat16 b[8]; ushort4 u[2]; } cv;
      cv.b[0] = __float2bfloat16(xprev.x); cv.b[1] = __float2bfloat16(xprev.y);
      cv.b[2] = __float2bfloat16(xprev.z); cv.b[3] = __float2bfloat16(xprev.w);
      cv.b[4] = __float2bfloat16(xv.x);    cv.b[5] = __float2bfloat16(xv.y);
      cv.b[6] = __float2bfloat16(xv.z);    cv.b[7] = __float2bfloat16(xv.w);
      *(ushort4*)(xbq + 4 * (k - 1)) = cv.u[0];
      *(ushort4*)(xbq + 4 * k) = cv.u[1];
    } else {
      xprev = xv;
    }
  }
  // 2-step butterfly within each 4-lane group -> all 4 lanes hold full sums
#pragma unroll
  for (int e = 0; e < 16; e++) {
    acc[e] += __shfl_xor(acc[e], 1, 64);
    acc[e] += __shfl_xor(acc[e], 2, 64);
  }
  const float4 nz0 = *(const float4*)(noise + (size_t)tok * 8);
  const float4 nz1 = *(const float4*)(noise + (size_t)tok * 8 + 4);
  const float nzv[8] = {nz0.x, nz0.y, nz0.z, nz0.w, nz1.x, nz1.y, nz1.z, nz1.w};
  float noisy[8];
#pragma unroll
  for (int e = 0; e < 8; e++) {
    float z = acc[8 + e] + bn[e];
    float spv = fmaxf(z, 0.f) + log1pf(expf(-fabsf(z)));  // softplus
    noisy[e] = acc[e] + bw[e] + nzv[e] * spv;
  }
  int i0 = 0; float v0 = noisy[0];
#pragma unroll
  for (int e = 1; e < 8; e++)
    if (noisy[e] > v0) { v0 = noisy[e]; i0 = e; }
  int i1 = -1; float v1 = -3.4e38f;
#pragma unroll
  for (int e = 0; e < 8; e++)
    if (e != i0 && noisy[e] > v1) { v1 = noisy[e]; i1 = e; }
  float ex = expf(v1 - v0);
  float inv = 1.f / (1.f + ex);
  if (q == 0) {
    re[tok] = make_int2(i0, i1);
    rp[tok] = make_float2(inv, ex * inv);
  }
}

// ---------------- per-expert capacity scan (token order == reference cumsum) ----------------
__global__ __launch_bounds__(1024) void scan_kernel(const int2* __restrict__ re,
                                                    const float2* __restrict__ rp,
                                                    int* __restrict__ tokl,
                                                    float* __restrict__ wgtl) {
  const int e = blockIdx.x;
  const int tid = threadIdx.x;
  const int lane = tid & 63, wid = tid >> 6;
  __shared__ int wcount[16];
  int base = 0;
  int2 ee = re[tid];
  float2 pp = rp[tid];
  for (int c = 0; c < NTOK; c += 1024) {
    int2 ee_n; float2 pp_n;
    const int tn = c + 1024 + tid;
    if (tn < NTOK) { ee_n = re[tn]; pp_n = rp[tn]; }
    const int t = c + tid;
    const bool m = (ee.x == e) || (ee.y == e);
    unsigned long long bal = __ballot(m);
    int lanepre = __popcll(bal & ((1ull << lane) - 1ull));
    if (lane == 0) wcount[wid] = __popcll(bal);
    __syncthreads();
    int woff = 0, ctot = 0;
#pragma unroll
    for (int w = 0; w < 16; w++) {
      int cw = wcount[w];
      woff += (w < wid) ? cw : 0;
      ctot += cw;
    }
    const int pos = base + woff + lanepre;
    if (m && pos < CAPACITY) {
      tokl[(size_t)e * CAPACITY + pos] = t;
      wgtl[(size_t)e * CAPACITY + pos] = (ee.x == e) ? pp.x : pp.y;
    }
    base += ctot;
    __syncthreads();
    ee = ee_n; pp = pp_n;
  }
}

// ---------------- GEMM1: h = relu(gather(xb) @ W1[e]^T + b1[e]) ----------------
// 256x256/BK=64, 8 waves, 8-phase counted-vmcnt (validated R3), pair-batched over z.
#define MFMA_QUAD(MH, NH, BF)                                                        \
  _Pragma("unroll") for (int m = 0; m < 4; m++)                                      \
  _Pragma("unroll") for (int n = 0; n < 2; n++)                                      \
  _Pragma("unroll") for (int kk = 0; kk < 2; kk++)                                   \
    acc[(MH)*4 + m][(NH)*2 + n] = __builtin_amdgcn_mfma_f32_16x16x32_bf16(           \
        af[m][kk], BF[n][kk], acc[(MH)*4 + m][(NH)*2 + n], 0, 0, 0);

__global__ __launch_bounds__(512, 2) void gemm1_kernel(
    const __hip_bfloat16* __restrict__ xb,   // [NTOK][512]
    const __hip_bfloat16* __restrict__ w1b,  // [8][2048][512]
    const float* __restrict__ b1,            // [8][2048]
    const int* __restrict__ toklb,           // [8][CAPACITY]
    __hip_bfloat16* __restrict__ hb,         // [2][CAPACITY][2048]
    int e0) {
  extern __shared__ char lds[];              // 131072 B
  // XCD-chunked swizzle of flat 512-block grid; decode (bn 8, bm 32, z 2)
  const int nbid = blockIdx.x;
  const int id = (nbid & 7) * 64 + (nbid >> 3);
  const int bn = id & 7, bm = (id >> 3) & 31, z = id >> 8;
  const int e = e0 + z;
  const __hip_bfloat16* w1 = w1b + (size_t)e * HDIM * DMODEL;
  const int* tokl = toklb + (size_t)e * CAPACITY;
  __hip_bfloat16* h = hb + (size_t)z * CAPACITY * HDIM;

  const int tid = threadIdx.x;
  const int lane = tid & 63;
  const int wid = tid >> 6;
  const int wr = wid >> 2, wc = wid & 3;

  const int rowsel = tid >> 3;                                // 0..63
  const int colsw = 8 * ((tid & 7) ^ (rowsel & 7));           // inverse-swizzled src col
  const __hip_bfloat16* srcA[2][2];
  const __hip_bfloat16* srcB[2][2];
#pragma unroll
  for (int hh = 0; hh < 2; hh++)
#pragma unroll
    for (int j = 0; j < 2; j++) {
      const int arow = j * 128 + hh * 64 + rowsel;            // logical A row
      srcA[hh][j] = xb + (size_t)tokl[bm * 256 + arow] * DMODEL + colsw;
      const int prow = j * 64 + rowsel;                       // physical B row in half
      const int brow = (prow >> 5) * 64 + hh * 32 + (prow & 31);
      srcB[hh][j] = w1 + (size_t)(bn * 256 + brow) * DMODEL + colsw;
    }
  const int wub = wid * 1024;

  auto stageA = [&](int hh, int t) {
    char* base = lds + ((t & 1) * 65536) + hh * 16384 + wub;
    gload16(srcA[hh][0] + t * 64, base);
    gload16(srcA[hh][1] + t * 64, base + 8192);
  };
  auto stageB = [&](int hh, int t) {
    char* base = lds + ((t & 1) * 65536) + 32768 + hh * 16384 + wub;
    gload16(srcB[hh][0] + t * 64, base);
    gload16(srcB[hh][1] + t * 64, base + 8192);
  };

  const int cs0 = ((lane >> 4) * 16) ^ ((lane & 7) << 4);
  const int arowoff = (wr * 64 + (lane & 15)) * 128;
  const int browoff = (wc * 32 + (lane & 15)) * 128;

  f32x4 acc[8][4];
#pragma unroll
  for (int m = 0; m < 8; m++)
#pragma unroll
    for (int n = 0; n < 4; n++) acc[m][n] = (f32x4){0.f, 0.f, 0.f, 0.f};

  stageA(0, 0); stageB(0, 0); stageA(1, 0); stageB(1, 0);
  stageA(0, 1); stageB(0, 1); stageB(1, 1);
  asm volatile("s_waitcnt vmcnt(6)" ::: "memory");
  __builtin_amdgcn_s_barrier();

  s16x8 af[4][2], bf0[2][2], bf1[2][2];
  const int NT = DMODEL / 64;  // 8 K-tiles
  for (int w = 0; w < NT; w++) {
    char* La = lds + (w & 1) * 65536;
    char* Lb = La + 32768;
    // P1: (mh0,nh0); stage Ah1(w+1)
#pragma unroll
    for (int m = 0; m < 4; m++)
#pragma unroll
      for (int kk = 0; kk < 2; kk++)
        af[m][kk] = *(const s16x8*)(La + arowoff + m * 2048 + (cs0 ^ (kk << 6)));
#pragma unroll
    for (int n = 0; n < 2; n++)
#pragma unroll
      for (int kk = 0; kk < 2; kk++)
        bf0[n][kk] = *(const s16x8*)(Lb + browoff + n * 2048 + (cs0 ^ (kk << 6)));
    if (w + 1 < NT) stageA(1, w + 1);
    __builtin_amdgcn_s_barrier();
    asm volatile("s_waitcnt lgkmcnt(0)" ::: "memory");
    __builtin_amdgcn_sched_barrier(0);
    __builtin_amdgcn_s_setprio(1);
    MFMA_QUAD(0, 0, bf0)
    __builtin_amdgcn_s_setprio(0);
    __builtin_amdgcn_s_barrier();
    // P2: (mh0,nh1); stage Ah0(w+2)
#pragma unroll
    for (int n = 0; n < 2; n++)
#pragma unroll
      for (int kk = 0; kk < 2; kk++)
        bf1[n][kk] = *(const s16x8*)(Lb + 16384 + browoff + n * 2048 + (cs0 ^ (kk << 6)));
    if (w + 2 < NT) stageA(0, w + 2);
    __builtin_amdgcn_s_barrier();
    asm volatile("s_waitcnt lgkmcnt(0)" ::: "memory");
    __builtin_amdgcn_sched_barrier(0);
    __builtin_amdgcn_s_setprio(1);
    MFMA_QUAD(0, 1, bf1)
    __builtin_amdgcn_s_setprio(0);
    __builtin_amdgcn_s_barrier();
    // P3: (mh1,nh0); stage Bh0(w+2)
#pragma unroll
    for (int m = 0; m < 4; m++)
#pragma unroll
      for (int kk = 0; kk < 2; kk++)
        af[m][kk] = *(const s16x8*)(La + 16384 + arowoff + m * 2048 + (cs0 ^ (kk << 6)));
    if (w + 2 < NT) stageB(0, w + 2);
    __builtin_amdgcn_s_barrier();
    asm volatile("s_waitcnt lgkmcnt(0)" ::: "memory");
    __builtin_amdgcn_sched_barrier(0);
    __builtin_amdgcn_s_setprio(1);
    MFMA_QUAD(1, 0, bf0)
    __builtin_amdgcn_s_setprio(0);
    __builtin_amdgcn_s_barrier();
    // P4: (mh1,nh1); stage Bh1(w+2); boundary vmcnt
    if (w + 2 < NT) stageB(1, w + 2);
    if (w == NT - 2) { asm volatile("s_waitcnt vmcnt(0)" ::: "memory"); }
    else             { asm volatile("s_waitcnt vmcnt(6)" ::: "memory"); }
    __builtin_amdgcn_s_barrier();
    __builtin_amdgcn_s_setprio(1);
    MFMA_QUAD(1, 1, bf1)
    __builtin_amdgcn_s_setprio(0);
    __builtin_amdgcn_s_barrier();
  }

#pragma unroll
  for (int nn = 0; nn < 4; nn++) {
    const int col = bn * 256 + wc * 64 + nn * 16 + (lane & 15);
    const float bias = b1[(size_t)e * HDIM + col];
#pragma unroll
    for (int m = 0; m < 8; m++) {
      const int row0 = bm * 256 + wr * 128 + m * 16 + ((lane >> 4) << 2);
#pragma unroll
      for (int q = 0; q < 4; q++) {
        float v = acc[m][nn][q] + bias;
        h[(size_t)(row0 + q) * HDIM + col] = __float2bfloat16(fmaxf(v, 0.f));
      }
    }
  }
}

// ---------------- GEMM2: out[tok] += w * (h @ W2[e]^T + b2[e]) ----------------
// 128x128/BK=64, 4 waves, swizzled LDS (conflict-free ds_read_b128), pair-batched
// over z, XCD-chunked swizzle, fp32 atomicAdd scatter epilogue.
__global__ __launch_bounds__(256, 2) void gemm2_kernel(
    const __hip_bfloat16* __restrict__ hb,   // [2][CAPACITY][2048]
    const __hip_bfloat16* __restrict__ w2b,  // [8][512][2048]
    const float* __restrict__ b2,            // [8][512]
    const int* __restrict__ toklb, const float* __restrict__ wgtlb,  // [8][CAP]
    float* __restrict__ out, int e0) {       // [NTOK][512]
  __shared__ char lds[32768];                // A [128][64] @0, B [128][64] @16384
  const int nbid = blockIdx.x;
  const int id = (nbid & 7) * 64 + (nbid >> 3);   // XCD chunking (512 % 8 == 0)
  const int bn = id & 3, bm = (id >> 2) & 63, z = id >> 8;
  const int e = e0 + z;
  const __hip_bfloat16* hA = hb + (size_t)z * CAPACITY * HDIM;
  const __hip_bfloat16* w2 = w2b + (size_t)e * DMODEL * HDIM;
  const int* tokl = toklb + (size_t)e * CAPACITY;
  const float* wgtl = wgtlb + (size_t)e * CAPACITY;

  const int tid = threadIdx.x, lane = tid & 63, wid = tid >> 6;
  const int wr = wid >> 1, wc = wid & 1;

  // stage: row = j*32 + (tid>>3), slot = tid&7; LDS[prow][s] = global[prow][s^(prow&7)]
  const int colsw = 8 * ((tid & 7) ^ ((tid >> 3) & 7));
  const __hip_bfloat16* srcA = hA + (size_t)(bm * 128 + (tid >> 3)) * HDIM + colsw;
  const __hip_bfloat16* srcB = w2 + (size_t)(bn * 128 + (tid >> 3)) * HDIM + colsw;
  const int wub = wid * 1024;

  const int cs0 = ((lane >> 4) * 16) ^ ((lane & 7) << 4);
  const int arowoff = (wr * 64 + (lane & 15)) * 128;
  const int browoff = (wc * 64 + (lane & 15)) * 128;

  f32x4 acc[4][4];
#pragma unroll
  for (int m = 0; m < 4; m++)
#pragma unroll
    for (int n = 0; n < 4; n++) acc[m][n] = (f32x4){0.f, 0.f, 0.f, 0.f};

  for (int ks = 0; ks < HDIM; ks += 64) {
#pragma unroll
    for (int j = 0; j < 4; j++)
      gload16(srcA + (size_t)j * 32 * HDIM + ks, lds + j * 4096 + wub);
#pragma unroll
    for (int j = 0; j < 4; j++)
      gload16(srcB + (size_t)j * 32 * HDIM + ks, lds + 16384 + j * 4096 + wub);
    __syncthreads();  // compiler drains vmcnt+lgkmcnt before barrier
    s16x8 af[4][2], bf[4][2];
#pragma unroll
    for (int m = 0; m < 4; m++)
#pragma unroll
      for (int kk = 0; kk < 2; kk++)
        af[m][kk] = *(const s16x8*)(lds + arowoff + m * 2048 + (cs0 ^ (kk << 6)));
#pragma unroll
    for (int n = 0; n < 4; n++)
#pragma unroll
      for (int kk = 0; kk < 2; kk++)
        bf[n][kk] = *(const s16x8*)(lds + 16384 + browoff + n * 2048 + (cs0 ^ (kk << 6)));
#pragma unroll
    for (int m = 0; m < 4; m++)
#pragma unroll
      for (int n = 0; n < 4; n++)
#pragma unroll
        for (int kk = 0; kk < 2; kk++)
          acc[m][n] = __builtin_amdgcn_mfma_f32_16x16x32_bf16(af[m][kk], bf[n][kk], acc[m][n], 0, 0, 0);
    __syncthreads();
  }

  // epilogue: atomic weighted scatter (C/D: col=lane&15, row=(lane>>4)*4+q)
  int colv[4]; float biasv[4];
#pragma unroll
  for (int n = 0; n < 4; n++) {
    colv[n] = bn * 128 + wc * 64 + n * 16 + (lane & 15);
    biasv[n] = b2[(size_t)e * DMODEL + colv[n]];
  }
#pragma unroll
  for (int m = 0; m < 4; m++) {
    const int slot0 = bm * 128 + wr * 64 + m * 16 + ((lane >> 4) << 2);
#pragma unroll
    for (int q = 0; q < 4; q++) {
      const int slot = slot0 + q;
      const int t = tokl[slot];
      const float w = wgtl[slot];
      if (w != 0.f) {
        float* op = out + (size_t)t * DMODEL;
#pragma unroll
        for (int n = 0; n < 4; n++)
          atomicAdd(op + colv[n], (acc[m][n][q] + biasv[n]) * w);
      }
    }
  }
}

extern "C" void kernel_launch(void* const* d_in, const int* in_sizes, int n_in,
                              void* d_out, int out_size, void* d_ws, size_t ws_size,
                              hipStream_t stream) {
  const float* x  = (const float*)d_in[0];
  const float* noise = (const float*)d_in[1];
  const float* Ww = (const float*)d_in[2];
  const float* bw = (const float*)d_in[3];
  const float* Wn = (const float*)d_in[4];
  const float* bn = (const float*)d_in[5];
  const float* W1 = (const float*)d_in[6];
  const float* b1 = (const float*)d_in[7];
  const float* W2 = (const float*)d_in[8];
  const float* b2 = (const float*)d_in[9];
  float* out = (float*)d_out;

  // workspace layout (bytes); 1 MB = 1<<20
  char* ws = (char*)d_ws;
  __hip_bfloat16* xb  = (__hip_bfloat16*)(ws);                        // 32 MB [NTOK][512]
  __hip_bfloat16* w1b = (__hip_bfloat16*)(ws + (32ull << 20));        // 16 MB [8][2048][512]
  __hip_bfloat16* w2b = (__hip_bfloat16*)(ws + (48ull << 20));        // 16 MB [8][512][2048]
  __hip_bfloat16* hb  = (__hip_bfloat16*)(ws + (64ull << 20));        // 64 MB [2][8192][2048]
  int2*   re   = (int2*)(ws + (128ull << 20));                        // 256 KB
  float2* rp   = (float2*)(ws + (128ull << 20) + 262144);             // 256 KB
  int*    tokl = (int*)(ws + (128ull << 20) + 524288);                // 256 KB [8][8192]
  float*  wgtl = (float*)(ws + (128ull << 20) + 786432);              // 256 KB [8][8192]

  (void)hipFuncSetAttribute((const void*)gemm1_kernel,
                            hipFuncAttributeMaxDynamicSharedMemorySize, 131072);

  hipMemsetAsync(d_out, 0, (size_t)NTOK * DMODEL * sizeof(float), stream);
  hipMemsetAsync(tokl, 0, 2 * NEXP * CAPACITY * sizeof(int), stream);  // tokl+wgtl contiguous

  cvt_bf16_kernel<<<1024, 256, 0, stream>>>(W1, w1b, NEXP * HDIM * DMODEL);
  cvt_bf16_kernel<<<1024, 256, 0, stream>>>(W2, w2b, NEXP * HDIM * DMODEL);
  router_kernel<<<NTOK / 64, 256, 0, stream>>>(x, noise, Ww, bw, Wn, bn, xb, re, rp);
  scan_kernel<<<NEXP, 1024, 0, stream>>>(re, rp, tokl, wgtl);

  for (int ep = 0; ep < 4; ep++) {
    const int e0 = 2 * ep;
    gemm1_kernel<<<512, 512, 131072, stream>>>(xb, w1b, b1, tokl, hb, e0);
    gemm2_kernel<<<512, 256, 0, stream>>>(hb, w2b, b2, tokl, wgtl, out, e0);
  }
}

// Round 6
// 592.872 us; speedup vs baseline: 1.7681x; 1.3444x over previous
//
#include <hip/hip_runtime.h>
#include <hip/hip_bf16.h>
#include <stdint.h>

// SparseMoE: N=32768 tokens, D=512, H=2048, 8 experts, top-2, capacity=8192.
// R5 (resubmit after infra timeout): router = 16-lanes-per-token (8192 waves);
//     gemm2 = dbuf 2-phase + y-buffer epilogue (no atomics) with ws_size-adaptive
//     fallback to atomic scatter; combine kernel applies router weight + b2.

#define NTOK     32768
#define DMODEL   512
#define HDIM     2048
#define NEXP     8
#define CAPACITY 8192

typedef __attribute__((ext_vector_type(4))) float f32x4;
typedef __attribute__((ext_vector_type(8))) short s16x8;

#define GLOBAL_AS __attribute__((address_space(1)))
#define LDS_AS    __attribute__((address_space(3)))

__device__ __forceinline__ void gload16(const void* g, void* l) {
  __builtin_amdgcn_global_load_lds((const GLOBAL_AS void*)g, (LDS_AS void*)l, 16, 0, 0);
}
__device__ __forceinline__ float bf2f(short s) {
  union { unsigned u; float f; } cv; cv.u = ((unsigned)(unsigned short)s) << 16; return cv.f;
}

// ---------------- fp32 -> bf16 convert (weights) ----------------
__global__ __launch_bounds__(256) void cvt_bf16_kernel(const float* __restrict__ s,
                                                       __hip_bfloat16* __restrict__ d, int n) {
  int stride = gridDim.x * blockDim.x * 4;
  for (int i = (blockIdx.x * blockDim.x + threadIdx.x) * 4; i < n; i += stride) {
    float4 v = *(const float4*)(s + i);
    union { __hip_bfloat16 b[4]; ushort4 u; } cv;
    cv.b[0] = __float2bfloat16(v.x);
    cv.b[1] = __float2bfloat16(v.y);
    cv.b[2] = __float2bfloat16(v.z);
    cv.b[3] = __float2bfloat16(v.w);
    *(ushort4*)(d + i) = cv.u;
  }
}

// ---------------- router: 16 lanes per token ----------------
// 4 tokens/wave, 16 tokens/block, 2048 blocks => 8192 waves (full occupancy potential).
// Dot: 8 float4 iters/lane (coalesced 256B/group). Fold: 15 shfl (halving multi-value
// butterfly). Tail: softplus on lanes 8-15, top-2 via 3-step shfl reduce on lanes 0-7.
__global__ __launch_bounds__(256) void router_kernel(
    const float* __restrict__ x, const float* __restrict__ noise,
    const float* __restrict__ Ww, const float* __restrict__ bw,
    const float* __restrict__ Wn, const float* __restrict__ bn,
    __hip_bfloat16* __restrict__ xb, int2* __restrict__ re, float2* __restrict__ rp) {
  const int tid = threadIdx.x;
  const int i = tid & 15;                       // lane within 16-lane token group
  const int tok = blockIdx.x * 16 + (tid >> 4);
  const float* xrow = x + (size_t)tok * DMODEL;
  __hip_bfloat16* xbrow = xb + (size_t)tok * DMODEL;

  float acc[16];
#pragma unroll
  for (int e = 0; e < 16; e++) acc[e] = 0.f;
#pragma unroll
  for (int k = 0; k < 8; k++) {
    const int off = k * 64 + i * 4;
    const float4 xv = *(const float4*)(xrow + off);
    union { __hip_bfloat16 b[4]; ushort4 u; } cv;  // fused bf16 conversion (8B store)
    cv.b[0] = __float2bfloat16(xv.x); cv.b[1] = __float2bfloat16(xv.y);
    cv.b[2] = __float2bfloat16(xv.z); cv.b[3] = __float2bfloat16(xv.w);
    *(ushort4*)(xbrow + off) = cv.u;
#pragma unroll
    for (int e = 0; e < 8; e++) {
      const float4 a = *(const float4*)(Ww + e * DMODEL + off);
      acc[e] = fmaf(xv.w, a.w, fmaf(xv.z, a.z, fmaf(xv.y, a.y, fmaf(xv.x, a.x, acc[e]))));
      const float4 b = *(const float4*)(Wn + e * DMODEL + off);
      acc[8 + e] = fmaf(xv.w, b.w, fmaf(xv.z, b.z, fmaf(xv.y, b.y, fmaf(xv.x, b.x, acc[8 + e]))));
    }
  }
  // halving fold: after all steps, lane i holds full sum of value i (within its group)
#define FOLD(W)                                                         \
  {                                                                     \
    const bool hi = (i & (W)) != 0;                                     \
    _Pragma("unroll") for (int j = 0; j < (W); j++) {                   \
      float sent = hi ? acc[j] : acc[j + (W)];                          \
      float r = __shfl_xor(sent, (W), 64);                              \
      acc[j] = (hi ? acc[j + (W)] : acc[j]) + r;                        \
    }                                                                   \
  }
  FOLD(8) FOLD(4) FOLD(2) FOLD(1)
#undef FOLD
  // lanes 8-15: softplus of noise logit; lanes 0-7 fetch it via shfl
  const float bnv = bn[i & 7];
  const float z = acc[0] + bnv;
  const float spv = fmaxf(z, 0.f) + log1pf(expf(-fabsf(z)));
  const float spo = __shfl_xor(spv, 8, 64);
  const float nzl = noise[(size_t)tok * 8 + (i & 7)];
  const float noisy = acc[0] + bw[i & 7] + nzl * spo;  // valid on lanes i<8
  // top-1 (ties -> lower index) over the 8 lanes
  float bv = noisy; int bi = i;
#pragma unroll
  for (int off = 1; off <= 4; off <<= 1) {
    float ov = __shfl_xor(bv, off, 64);
    int oi = __shfl_xor(bi, off, 64);
    if (ov > bv || (ov == bv && oi < bi)) { bv = ov; bi = oi; }
  }
  // second max, excluding bi
  float sv = (i == bi) ? -3.4e38f : noisy; int si = i;
#pragma unroll
  for (int off = 1; off <= 4; off <<= 1) {
    float ov = __shfl_xor(sv, off, 64);
    int oi = __shfl_xor(si, off, 64);
    if (ov > sv || (ov == sv && oi < si)) { sv = ov; si = oi; }
  }
  const float ex = expf(sv - bv);
  const float inv = 1.f / (1.f + ex);
  if (i == 0) {
    re[tok] = make_int2(bi, si);
    rp[tok] = make_float2(inv, ex * inv);
  }
}

// ---------------- per-expert capacity scan + token->slot map ----------------
__global__ __launch_bounds__(1024) void scan_kernel(const int2* __restrict__ re,
                                                    const float2* __restrict__ rp,
                                                    int* __restrict__ tokl,
                                                    float* __restrict__ wgtl,
                                                    int* __restrict__ sm0,
                                                    int* __restrict__ sm1) {
  const int e = blockIdx.x;
  const int tid = threadIdx.x;
  const int lane = tid & 63, wid = tid >> 6;
  __shared__ int wcount[16];
  int base = 0;
  int2 ee = re[tid];
  float2 pp = rp[tid];
  for (int c = 0; c < NTOK; c += 1024) {
    int2 ee_n; float2 pp_n;
    const int tn = c + 1024 + tid;
    if (tn < NTOK) { ee_n = re[tn]; pp_n = rp[tn]; }
    const int t = c + tid;
    const bool m = (ee.x == e) || (ee.y == e);
    unsigned long long bal = __ballot(m);
    int lanepre = __popcll(bal & ((1ull << lane) - 1ull));
    if (lane == 0) wcount[wid] = __popcll(bal);
    __syncthreads();
    int woff = 0, ctot = 0;
#pragma unroll
    for (int w = 0; w < 16; w++) {
      int cw = wcount[w];
      woff += (w < wid) ? cw : 0;
      ctot += cw;
    }
    const int pos = base + woff + lanepre;
    if (m) {
      const int slotv = (pos < CAPACITY) ? pos : -1;
      if (ee.x == e) sm0[t] = slotv; else sm1[t] = slotv;  // each written by exactly one block
      if (pos < CAPACITY) {
        tokl[(size_t)e * CAPACITY + pos] = t;
        wgtl[(size_t)e * CAPACITY + pos] = (ee.x == e) ? pp.x : pp.y;
      }
    }
    base += ctot;
    __syncthreads();
    ee = ee_n; pp = pp_n;
  }
}

// ---------------- GEMM1: h = relu(gather(xb) @ W1[e]^T + b1[e]) ----------------
// 256x256/BK=64, 8 waves, 8-phase counted-vmcnt (validated R3/R4), pair-batched over z.
#define MFMA_QUAD(MH, NH, BF)                                                        \
  _Pragma("unroll") for (int m = 0; m < 4; m++)                                      \
  _Pragma("unroll") for (int n = 0; n < 2; n++)                                      \
  _Pragma("unroll") for (int kk = 0; kk < 2; kk++)                                   \
    acc[(MH)*4 + m][(NH)*2 + n] = __builtin_amdgcn_mfma_f32_16x16x32_bf16(           \
        af[m][kk], BF[n][kk], acc[(MH)*4 + m][(NH)*2 + n], 0, 0, 0);

__global__ __launch_bounds__(512, 2) void gemm1_kernel(
    const __hip_bfloat16* __restrict__ xb,   // [NTOK][512]
    const __hip_bfloat16* __restrict__ w1b,  // [8][2048][512]
    const float* __restrict__ b1,            // [8][2048]
    const int* __restrict__ toklb,           // [8][CAPACITY]
    __hip_bfloat16* __restrict__ hb,         // [2][CAPACITY][2048]
    int e0) {
  extern __shared__ char lds[];              // 131072 B
  const int nbid = blockIdx.x;
  const int id = (nbid & 7) * 64 + (nbid >> 3);   // XCD chunking (512 % 8 == 0)
  const int bn = id & 7, bm = (id >> 3) & 31, z = id >> 8;
  const int e = e0 + z;
  const __hip_bfloat16* w1 = w1b + (size_t)e * HDIM * DMODEL;
  const int* tokl = toklb + (size_t)e * CAPACITY;
  __hip_bfloat16* h = hb + (size_t)z * CAPACITY * HDIM;

  const int tid = threadIdx.x;
  const int lane = tid & 63;
  const int wid = tid >> 6;
  const int wr = wid >> 2, wc = wid & 3;

  const int rowsel = tid >> 3;
  const int colsw = 8 * ((tid & 7) ^ (rowsel & 7));
  const __hip_bfloat16* srcA[2][2];
  const __hip_bfloat16* srcB[2][2];
#pragma unroll
  for (int hh = 0; hh < 2; hh++)
#pragma unroll
    for (int j = 0; j < 2; j++) {
      const int arow = j * 128 + hh * 64 + rowsel;
      srcA[hh][j] = xb + (size_t)tokl[bm * 256 + arow] * DMODEL + colsw;
      const int prow = j * 64 + rowsel;
      const int brow = (prow >> 5) * 64 + hh * 32 + (prow & 31);
      srcB[hh][j] = w1 + (size_t)(bn * 256 + brow) * DMODEL + colsw;
    }
  const int wub = wid * 1024;

  auto stageA = [&](int hh, int t) {
    char* base = lds + ((t & 1) * 65536) + hh * 16384 + wub;
    gload16(srcA[hh][0] + t * 64, base);
    gload16(srcA[hh][1] + t * 64, base + 8192);
  };
  auto stageB = [&](int hh, int t) {
    char* base = lds + ((t & 1) * 65536) + 32768 + hh * 16384 + wub;
    gload16(srcB[hh][0] + t * 64, base);
    gload16(srcB[hh][1] + t * 64, base + 8192);
  };

  const int cs0 = ((lane >> 4) * 16) ^ ((lane & 7) << 4);
  const int arowoff = (wr * 64 + (lane & 15)) * 128;
  const int browoff = (wc * 32 + (lane & 15)) * 128;

  f32x4 acc[8][4];
#pragma unroll
  for (int m = 0; m < 8; m++)
#pragma unroll
    for (int n = 0; n < 4; n++) acc[m][n] = (f32x4){0.f, 0.f, 0.f, 0.f};

  stageA(0, 0); stageB(0, 0); stageA(1, 0); stageB(1, 0);
  stageA(0, 1); stageB(0, 1); stageB(1, 1);
  asm volatile("s_waitcnt vmcnt(6)" ::: "memory");
  __builtin_amdgcn_s_barrier();

  s16x8 af[4][2], bf0[2][2], bf1[2][2];
  const int NT = DMODEL / 64;
  for (int w = 0; w < NT; w++) {
    char* La = lds + (w & 1) * 65536;
    char* Lb = La + 32768;
#pragma unroll
    for (int m = 0; m < 4; m++)
#pragma unroll
      for (int kk = 0; kk < 2; kk++)
        af[m][kk] = *(const s16x8*)(La + arowoff + m * 2048 + (cs0 ^ (kk << 6)));
#pragma unroll
    for (int n = 0; n < 2; n++)
#pragma unroll
      for (int kk = 0; kk < 2; kk++)
        bf0[n][kk] = *(const s16x8*)(Lb + browoff + n * 2048 + (cs0 ^ (kk << 6)));
    if (w + 1 < NT) stageA(1, w + 1);
    __builtin_amdgcn_s_barrier();
    asm volatile("s_waitcnt lgkmcnt(0)" ::: "memory");
    __builtin_amdgcn_sched_barrier(0);
    __builtin_amdgcn_s_setprio(1);
    MFMA_QUAD(0, 0, bf0)
    __builtin_amdgcn_s_setprio(0);
    __builtin_amdgcn_s_barrier();
#pragma unroll
    for (int n = 0; n < 2; n++)
#pragma unroll
      for (int kk = 0; kk < 2; kk++)
        bf1[n][kk] = *(const s16x8*)(Lb + 16384 + browoff + n * 2048 + (cs0 ^ (kk << 6)));
    if (w + 2 < NT) stageA(0, w + 2);
    __builtin_amdgcn_s_barrier();
    asm volatile("s_waitcnt lgkmcnt(0)" ::: "memory");
    __builtin_amdgcn_sched_barrier(0);
    __builtin_amdgcn_s_setprio(1);
    MFMA_QUAD(0, 1, bf1)
    __builtin_amdgcn_s_setprio(0);
    __builtin_amdgcn_s_barrier();
#pragma unroll
    for (int m = 0; m < 4; m++)
#pragma unroll
      for (int kk = 0; kk < 2; kk++)
        af[m][kk] = *(const s16x8*)(La + 16384 + arowoff + m * 2048 + (cs0 ^ (kk << 6)));
    if (w + 2 < NT) stageB(0, w + 2);
    __builtin_amdgcn_s_barrier();
    asm volatile("s_waitcnt lgkmcnt(0)" ::: "memory");
    __builtin_amdgcn_sched_barrier(0);
    __builtin_amdgcn_s_setprio(1);
    MFMA_QUAD(1, 0, bf0)
    __builtin_amdgcn_s_setprio(0);
    __builtin_amdgcn_s_barrier();
    if (w + 2 < NT) stageB(1, w + 2);
    if (w == NT - 2) { asm volatile("s_waitcnt vmcnt(0)" ::: "memory"); }
    else             { asm volatile("s_waitcnt vmcnt(6)" ::: "memory"); }
    __builtin_amdgcn_s_barrier();
    __builtin_amdgcn_s_setprio(1);
    MFMA_QUAD(1, 1, bf1)
    __builtin_amdgcn_s_setprio(0);
    __builtin_amdgcn_s_barrier();
  }

#pragma unroll
  for (int nn = 0; nn < 4; nn++) {
    const int col = bn * 256 + wc * 64 + nn * 16 + (lane & 15);
    const float bias = b1[(size_t)e * HDIM + col];
#pragma unroll
    for (int m = 0; m < 8; m++) {
      const int row0 = bm * 256 + wr * 128 + m * 16 + ((lane >> 4) << 2);
#pragma unroll
      for (int q = 0; q < 4; q++) {
        float v = acc[m][nn][q] + bias;
        h[(size_t)(row0 + q) * HDIM + col] = __float2bfloat16(fmaxf(v, 0.f));
      }
    }
  }
}

// ---------------- GEMM2: y[e][slot] = h_e[slot] @ W2[e]^T (dbuf 2-phase) ----------------
// 128x128/BK=64, 4 waves, double-buffered LDS (64KB -> 2 blocks/CU), swizzled reads,
// pair-batched over z, XCD-chunked. Epilogue: YP -> plain bf16 y stores (no atomics);
// fallback -> weighted atomic scatter to out (R4 semantics).
template <bool YP>
__global__ __launch_bounds__(256, 4) void gemm2_kernel(
    const __hip_bfloat16* __restrict__ hb,   // [2][CAPACITY][2048]
    const __hip_bfloat16* __restrict__ w2b,  // [8][512][2048]
    const float* __restrict__ b2,            // [8][512]
    const int* __restrict__ toklb, const float* __restrict__ wgtlb,
    float* __restrict__ out,                 // [NTOK][512]
    __hip_bfloat16* __restrict__ yb,         // [8][CAPACITY][512]
    int e0) {
  __shared__ char lds[65536];                // 2 x (A 16KB + B 16KB)
  const int nbid = blockIdx.x;
  const int id = (nbid & 7) * 64 + (nbid >> 3);
  const int bn = id & 3, bm = (id >> 2) & 63, z = id >> 8;
  const int e = e0 + z;
  const __hip_bfloat16* hA = hb + (size_t)z * CAPACITY * HDIM;
  const __hip_bfloat16* w2 = w2b + (size_t)e * DMODEL * HDIM;

  const int tid = threadIdx.x, lane = tid & 63, wid = tid >> 6;
  const int wr = wid >> 1, wc = wid & 1;

  const int colsw = 8 * ((tid & 7) ^ ((tid >> 3) & 7));
  const __hip_bfloat16* srcA = hA + (size_t)(bm * 128 + (tid >> 3)) * HDIM + colsw;
  const __hip_bfloat16* srcB = w2 + (size_t)(bn * 128 + (tid >> 3)) * HDIM + colsw;
  const int wub = wid * 1024;

  auto stage = [&](int buf, int ks) {
    char* base = lds + buf * 32768 + wub;
#pragma unroll
    for (int j = 0; j < 4; j++) {
      gload16(srcA + (size_t)j * 32 * HDIM + ks, base + j * 4096);
      gload16(srcB + (size_t)j * 32 * HDIM + ks, base + 16384 + j * 4096);
    }
  };

  const int cs0 = ((lane >> 4) * 16) ^ ((lane & 7) << 4);
  const int arowoff = (wr * 64 + (lane & 15)) * 128;
  const int browoff = (wc * 64 + (lane & 15)) * 128;

  f32x4 acc[4][4];
#pragma unroll
  for (int m = 0; m < 4; m++)
#pragma unroll
    for (int n = 0; n < 4; n++) acc[m][n] = (f32x4){0.f, 0.f, 0.f, 0.f};

  stage(0, 0);
  asm volatile("s_waitcnt vmcnt(0)" ::: "memory");
  __builtin_amdgcn_s_barrier();

  const int NT = HDIM / 64;  // 32 K-steps
  for (int t = 0; t < NT; t++) {
    if (t + 1 < NT) stage((t + 1) & 1, (t + 1) * 64);   // issue next-tile loads first
    char* L = lds + (t & 1) * 32768;
    s16x8 af[4][2], bf[4][2];
#pragma unroll
    for (int m = 0; m < 4; m++)
#pragma unroll
      for (int kk = 0; kk < 2; kk++)
        af[m][kk] = *(const s16x8*)(L + arowoff + m * 2048 + (cs0 ^ (kk << 6)));
#pragma unroll
    for (int n = 0; n < 4; n++)
#pragma unroll
      for (int kk = 0; kk < 2; kk++)
        bf[n][kk] = *(const s16x8*)(L + 16384 + browoff + n * 2048 + (cs0 ^ (kk << 6)));
    asm volatile("s_waitcnt lgkmcnt(0)" ::: "memory");
    __builtin_amdgcn_sched_barrier(0);
    __builtin_amdgcn_s_setprio(1);
#pragma unroll
    for (int m = 0; m < 4; m++)
#pragma unroll
      for (int n = 0; n < 4; n++)
#pragma unroll
        for (int kk = 0; kk < 2; kk++)
          acc[m][n] = __builtin_amdgcn_mfma_f32_16x16x32_bf16(af[m][kk], bf[n][kk], acc[m][n], 0, 0, 0);
    __builtin_amdgcn_s_setprio(0);
    asm volatile("s_waitcnt vmcnt(0)" ::: "memory");  // next tile fully landed
    __builtin_amdgcn_s_barrier();
  }

  if (YP) {
    // plain bf16 stores into slot-indexed y (rows exclusively owned)
    __hip_bfloat16* yrow = yb + (size_t)e * CAPACITY * DMODEL;
#pragma unroll
    for (int m = 0; m < 4; m++) {
      const int slot0 = bm * 128 + wr * 64 + m * 16 + ((lane >> 4) << 2);
#pragma unroll
      for (int q = 0; q < 4; q++) {
#pragma unroll
        for (int n = 0; n < 4; n++) {
          const int col = bn * 128 + wc * 64 + n * 16 + (lane & 15);
          yrow[(size_t)(slot0 + q) * DMODEL + col] = __float2bfloat16(acc[m][n][q]);
        }
      }
    }
  } else {
    const int* tokl = toklb + (size_t)e * CAPACITY;
    const float* wgtl = wgtlb + (size_t)e * CAPACITY;
    int colv[4]; float biasv[4];
#pragma unroll
    for (int n = 0; n < 4; n++) {
      colv[n] = bn * 128 + wc * 64 + n * 16 + (lane & 15);
      biasv[n] = b2[(size_t)e * DMODEL + colv[n]];
    }
#pragma unroll
    for (int m = 0; m < 4; m++) {
      const int slot0 = bm * 128 + wr * 64 + m * 16 + ((lane >> 4) << 2);
#pragma unroll
      for (int q = 0; q < 4; q++) {
        const int slot = slot0 + q;
        const int t = tokl[slot];
        const float w = wgtl[slot];
        if (w != 0.f) {
          float* op = out + (size_t)t * DMODEL;
#pragma unroll
          for (int n = 0; n < 4; n++)
            atomicAdd(op + colv[n], (acc[m][n][q] + biasv[n]) * w);
        }
      }
    }
  }
}

// ---------------- combine: out[t] = sum_j w_j * (y[e_j][slot_j] + b2[e_j]) ----------------
__global__ __launch_bounds__(256) void combine_kernel(
    const __hip_bfloat16* __restrict__ yb, const float* __restrict__ b2,
    const int2* __restrict__ re, const float2* __restrict__ rp,
    const int* __restrict__ sm0, const int* __restrict__ sm1,
    float* __restrict__ out) {
  const int tid = threadIdx.x, lane = tid & 63, wid = tid >> 6;
  const int tok = blockIdx.x * 4 + wid;
  const int2 ee = re[tok];
  const float2 pp = rp[tok];
  const int s0 = sm0[tok], s1 = sm1[tok];
  float o[8];
#pragma unroll
  for (int j = 0; j < 8; j++) o[j] = 0.f;
  if (s0 >= 0) {
    const s16x8 v = *(const s16x8*)(yb + ((size_t)ee.x * CAPACITY + s0) * DMODEL + lane * 8);
    const float* bp = b2 + (size_t)ee.x * DMODEL + lane * 8;
#pragma unroll
    for (int j = 0; j < 8; j++) o[j] += pp.x * (bf2f(v[j]) + bp[j]);
  }
  if (s1 >= 0) {
    const s16x8 v = *(const s16x8*)(yb + ((size_t)ee.y * CAPACITY + s1) * DMODEL + lane * 8);
    const float* bp = b2 + (size_t)ee.y * DMODEL + lane * 8;
#pragma unroll
    for (int j = 0; j < 8; j++) o[j] += pp.y * (bf2f(v[j]) + bp[j]);
  }
  float* op = out + (size_t)tok * DMODEL + lane * 8;
  *(float4*)op = (float4){o[0], o[1], o[2], o[3]};
  *(float4*)(op + 4) = (float4){o[4], o[5], o[6], o[7]};
}

extern "C" void kernel_launch(void* const* d_in, const int* in_sizes, int n_in,
                              void* d_out, int out_size, void* d_ws, size_t ws_size,
                              hipStream_t stream) {
  const float* x  = (const float*)d_in[0];
  const float* noise = (const float*)d_in[1];
  const float* Ww = (const float*)d_in[2];
  const float* bw = (const float*)d_in[3];
  const float* Wn = (const float*)d_in[4];
  const float* bn = (const float*)d_in[5];
  const float* W1 = (const float*)d_in[6];
  const float* b1 = (const float*)d_in[7];
  const float* W2 = (const float*)d_in[8];
  const float* b2 = (const float*)d_in[9];
  float* out = (float*)d_out;

  // workspace layout (bytes) — meta first so the atomic fallback fits in 129.25 MB
  char* ws = (char*)d_ws;
  int2*   re   = (int2*)(ws);                          // 256 KB
  float2* rp   = (float2*)(ws + 262144);               // 256 KB
  int*    tokl = (int*)(ws + 524288);                  // 256 KB [8][8192]
  float*  wgtl = (float*)(ws + 786432);                // 256 KB [8][8192]
  int*    sm0  = (int*)(ws + 1048576);                 // 128 KB [NTOK]
  int*    sm1  = (int*)(ws + 1179648);                 // 128 KB [NTOK]
  __hip_bfloat16* xb  = (__hip_bfloat16*)(ws + 1310720);              // 32 MB
  __hip_bfloat16* w1b = (__hip_bfloat16*)(ws + 34865152);             // 16 MB
  __hip_bfloat16* w2b = (__hip_bfloat16*)(ws + 51642368);             // 16 MB
  __hip_bfloat16* hb  = (__hip_bfloat16*)(ws + 68419584);             // 64 MB [2][8192][2048]
  __hip_bfloat16* yb  = (__hip_bfloat16*)(ws + 135528448);            // 64 MB [8][8192][512]
  const bool YP = ws_size >= 202637312ull;             // y-path fits?

  (void)hipFuncSetAttribute((const void*)gemm1_kernel,
                            hipFuncAttributeMaxDynamicSharedMemorySize, 131072);

  hipMemsetAsync(tokl, 0, 2 * NEXP * CAPACITY * sizeof(int), stream);  // tokl+wgtl
  if (!YP) hipMemsetAsync(d_out, 0, (size_t)NTOK * DMODEL * sizeof(float), stream);

  cvt_bf16_kernel<<<1024, 256, 0, stream>>>(W1, w1b, NEXP * HDIM * DMODEL);
  cvt_bf16_kernel<<<1024, 256, 0, stream>>>(W2, w2b, NEXP * HDIM * DMODEL);
  router_kernel<<<NTOK / 16, 256, 0, stream>>>(x, noise, Ww, bw, Wn, bn, xb, re, rp);
  scan_kernel<<<NEXP, 1024, 0, stream>>>(re, rp, tokl, wgtl, sm0, sm1);

  for (int ep = 0; ep < 4; ep++) {
    const int e0 = 2 * ep;
    gemm1_kernel<<<512, 512, 131072, stream>>>(xb, w1b, b1, tokl, hb, e0);
    if (YP)
      gemm2_kernel<true><<<512, 256, 0, stream>>>(hb, w2b, b2, tokl, wgtl, out, yb, e0);
    else
      gemm2_kernel<false><<<512, 256, 0, stream>>>(hb, w2b, b2, tokl, wgtl, out, yb, e0);
  }
  if (YP)
    combine_kernel<<<NTOK / 4, 256, 0, stream>>>(yb, b2, re, rp, sm0, sm1, out);
}